// Round 1
// baseline (319.576 us; speedup 1.0000x reference)
//
#include <hip/hip_runtime.h>
#include <stdint.h>

typedef __attribute__((ext_vector_type(8))) short short8;
typedef __attribute__((ext_vector_type(4))) float f32x4;

static __device__ __forceinline__ ushort f2bf(float f) {
  uint32_t u = __float_as_uint(f);
  uint32_t r = (u + 0x7FFFu + ((u >> 16) & 1u)) >> 16;
  return (ushort)r;
}

// ---------------------------------------------------------------------------
// KNN top-3 selection in f64 (exact selection vs f64 reference), weights f32.
// One thread per fine point; coarse positions staged in LDS (12 KB).
// ---------------------------------------------------------------------------
__global__ __launch_bounds__(256) void knn_kernel(
    const float* __restrict__ pos, const float* __restrict__ pos_skip,
    int4* __restrict__ idx_out, float4* __restrict__ w_out)
{
  __shared__ float pc[3072];
  const int b   = blockIdx.x >> 4;   // 16 blocks per batch
  const int blk = blockIdx.x & 15;
  for (int j = threadIdx.x; j < 3072; j += 256) pc[j] = pos[b * 3072 + j];
  __syncthreads();

  const int row = b * 4096 + blk * 256 + threadIdx.x;
  const double px = (double)pos_skip[(size_t)row * 3 + 0];
  const double py = (double)pos_skip[(size_t)row * 3 + 1];
  const double pz = (double)pos_skip[(size_t)row * 3 + 2];

  double b0 = 1e300, b1 = 1e300, b2 = 1e300;
  int i0 = 0, i1 = 0, i2 = 0;
  for (int i = 0; i < 1024; ++i) {
    double dx = (double)pc[i * 3 + 0] - px;
    double dy = (double)pc[i * 3 + 1] - py;
    double dz = (double)pc[i * 3 + 2] - pz;
    double d = dx * dx + dy * dy + dz * dz;
    if (d < b2) {
      if (d < b1) {
        b2 = b1; i2 = i1;
        if (d < b0) { b1 = b0; i1 = i0; b0 = d; i0 = i; }
        else        { b1 = d;  i1 = i; }
      } else { b2 = d; i2 = i; }
    }
  }
  double w0 = 1.0 / (sqrt(b0) + 1e-8);
  double w1 = 1.0 / (sqrt(b1) + 1e-8);
  double w2 = 1.0 / (sqrt(b2) + 1e-8);
  double den = w0 + w1 + w2 + 1e-8;
  idx_out[row] = make_int4(i0, i1, i2, 0);
  w_out[row] = make_float4((float)(w0 / den), (float)(w1 / den), (float)(w2 / den), 0.f);
}

// ---------------------------------------------------------------------------
// Gather 3 coarse feature rows, weighted sum -> bf16 into hcat[:, 0:512].
// 2 rows/block, 128 threads/row, float4 per thread (coalesced per-row).
// ---------------------------------------------------------------------------
__global__ __launch_bounds__(256) void interp_gather(
    const float* __restrict__ x, const int4* __restrict__ idx3,
    const float4* __restrict__ w3, ushort* __restrict__ hcat)
{
  const int row = blockIdx.x * 2 + (threadIdx.x >> 7);
  const int tc  = threadIdx.x & 127;
  const int b   = row >> 12;                 // 4096 fine rows per batch
  const int4 id = idx3[row];
  const float4 w = w3[row];
  const float4* f0 = (const float4*)(x + (size_t)(b * 1024 + id.x) * 512);
  const float4* f1 = (const float4*)(x + (size_t)(b * 1024 + id.y) * 512);
  const float4* f2 = (const float4*)(x + (size_t)(b * 1024 + id.z) * 512);
  const float4 a = f0[tc], c1 = f1[tc], c2 = f2[tc];
  float4 v;
  v.x = w.x * a.x + w.y * c1.x + w.z * c2.x;
  v.y = w.x * a.y + w.y * c1.y + w.z * c2.y;
  v.z = w.x * a.z + w.y * c1.z + w.z * c2.z;
  v.w = w.x * a.w + w.y * c1.w + w.z * c2.w;
  ushort4 o;
  o.x = f2bf(v.x); o.y = f2bf(v.y); o.z = f2bf(v.z); o.w = f2bf(v.w);
  *(ushort4*)(hcat + (size_t)row * 768 + tc * 4) = o;
}

// x_skip f32 -> bf16 into hcat[:, 512:768]
__global__ __launch_bounds__(256) void skip_copy(
    const float* __restrict__ xs, ushort* __restrict__ hcat)
{
  const int id  = blockIdx.x * 256 + threadIdx.x;  // one float4 per thread
  const int row = id >> 6;
  const int c4  = (id & 63) << 2;
  const float4 v = *(const float4*)(xs + (size_t)row * 256 + c4);
  ushort4 o;
  o.x = f2bf(v.x); o.y = f2bf(v.y); o.z = f2bf(v.z); o.w = f2bf(v.w);
  *(ushort4*)(hcat + (size_t)row * 768 + 512 + c4) = o;
}

// W [K][N] f32 -> Wt [N][K] bf16 (transpose so GEMM B-tiles load coalesced)
__global__ __launch_bounds__(256) void convert_wt(
    const float* __restrict__ W, ushort* __restrict__ Wt, int Kd, int Nd)
{
  const int id = blockIdx.x * 256 + threadIdx.x;
  if (id >= Kd * Nd) return;
  const int n = id / Kd, k = id - n * Kd;
  Wt[id] = f2bf(W[(size_t)k * Nd + n]);
}

// ---------------------------------------------------------------------------
// bf16 MFMA GEMM: C = relu(A[M][K] * Bt[N][K]^T + bias), 128x128 tile, BK=64,
// 4 waves (2x2), 4x4 fragments of 16x16x32 per wave, global_load_lds width 16.
// ---------------------------------------------------------------------------
template<int K, bool OUT_BF16>
__global__ __launch_bounds__(256, 2) void gemm_bias_relu(
    const ushort* __restrict__ A, const ushort* __restrict__ Bt,
    const float* __restrict__ bias, void* __restrict__ Cout, int M, int N)
{
  constexpr int BM = 128, BN = 128, BK = 64;
  __shared__ ushort Asm[BM * BK];   // 16 KB, row-major [128][64]
  __shared__ ushort Bsm[BN * BK];   // 16 KB, row-major [128][64]
  const int tid  = threadIdx.x;
  const int lane = tid & 63;
  const int wave = tid >> 6;
  const int nbn  = N / BN;
  const int bm   = blockIdx.x / nbn;
  const int bn   = blockIdx.x - bm * nbn;
  const int row0 = bm * BM, col0 = bn * BN;
  const int wr = wave >> 1, wc = wave & 1;
  const int so = tid * 16;   // byte offset within a 4KB staging chunk

  f32x4 acc[4][4] = {};

  for (int kt = 0; kt < K / BK; ++kt) {
    __syncthreads();   // previous tile's reads complete before overwrite
    const int kbase = kt * BK;
#pragma unroll
    for (int i = 0; i < 4; ++i) {
      const int o  = i * 4096 + so;     // linear byte offset in 16KB tile
      const int r  = o >> 7;            // row (128B per row)
      const int cu = (o & 127) >> 1;    // ushort offset within row
      const ushort* ga = A + (size_t)(row0 + r) * K + kbase + cu;
      __builtin_amdgcn_global_load_lds(
          (const __attribute__((address_space(1))) void*)ga,
          (__attribute__((address_space(3))) void*)((char*)Asm + o), 16, 0, 0);
      const ushort* gb = Bt + (size_t)(col0 + r) * K + kbase + cu;
      __builtin_amdgcn_global_load_lds(
          (const __attribute__((address_space(1))) void*)gb,
          (__attribute__((address_space(3))) void*)((char*)Bsm + o), 16, 0, 0);
    }
    __syncthreads();   // compiler emits vmcnt(0) drain before barrier

#pragma unroll
    for (int kk = 0; kk < 2; ++kk) {
      short8 af[4], bfr[4];
#pragma unroll
      for (int mi = 0; mi < 4; ++mi)
        af[mi] = *(const short8*)&Asm[(wr * 64 + mi * 16 + (lane & 15)) * BK + kk * 32 + (lane >> 4) * 8];
#pragma unroll
      for (int ni = 0; ni < 4; ++ni)
        bfr[ni] = *(const short8*)&Bsm[(wc * 64 + ni * 16 + (lane & 15)) * BK + kk * 32 + (lane >> 4) * 8];
#pragma unroll
      for (int mi = 0; mi < 4; ++mi)
#pragma unroll
        for (int ni = 0; ni < 4; ++ni)
          acc[mi][ni] = __builtin_amdgcn_mfma_f32_16x16x32_bf16(af[mi], bfr[ni], acc[mi][ni], 0, 0, 0);
    }
  }

  // epilogue: bias + relu; C/D layout: col = lane&15, row = (lane>>4)*4 + reg
  const int lc = lane & 15, lr = lane >> 4;
#pragma unroll
  for (int mi = 0; mi < 4; ++mi) {
#pragma unroll
    for (int ni = 0; ni < 4; ++ni) {
      const int col = col0 + wc * 64 + ni * 16 + lc;
      const float bv = bias[col];
      const int rbase = row0 + wr * 64 + mi * 16 + lr * 4;
#pragma unroll
      for (int r = 0; r < 4; ++r) {
        float v = acc[mi][ni][r] + bv;
        v = v > 0.f ? v : 0.f;
        if (OUT_BF16) ((ushort*)Cout)[(size_t)(rbase + r) * N + col] = f2bf(v);
        else          ((float*)Cout)[(size_t)(rbase + r) * N + col] = v;
      }
    }
  }
}

// ---------------------------------------------------------------------------
extern "C" void kernel_launch(void* const* d_in, const int* in_sizes, int n_in,
                              void* d_out, int out_size, void* d_ws, size_t ws_size,
                              hipStream_t stream) {
  const float* x        = (const float*)d_in[0];   // [16384, 512]
  const float* pos      = (const float*)d_in[1];   // [16384, 3]
  const float* x_skip   = (const float*)d_in[3];   // [65536, 256]
  const float* pos_skip = (const float*)d_in[4];   // [65536, 3]
  const float* W1       = (const float*)d_in[6];   // [768, 512]
  const float* b1       = (const float*)d_in[7];   // [512]
  const float* W2       = (const float*)d_in[8];   // [512, 512]
  const float* b2       = (const float*)d_in[9];   // [512]

  // d_out (134.2 MB f32) doubles as scratch for hcat bf16 (100.7 MB):
  // fully consumed by GEMM1 before GEMM2 overwrites d_out with the output.
  ushort* hcat = (ushort*)d_out;                       // [65536][768] bf16

  char* ws = (char*)d_ws;
  ushort* h2   = (ushort*)ws;                          // [65536][512] bf16, 67108864 B
  ushort* W1t  = (ushort*)(ws + 67108864);             // [512][768]  bf16, 786432 B
  ushort* W2t  = (ushort*)(ws + 67895296);             // [512][512]  bf16, 524288 B
  int4*   idx3 = (int4*)  (ws + 68419584);             // [65536] int4, 1 MB
  float4* w3   = (float4*)(ws + 69468160);             // [65536] float4, 1 MB

  knn_kernel<<<256, 256, 0, stream>>>(pos, pos_skip, idx3, w3);
  convert_wt<<<(768 * 512 + 255) / 256, 256, 0, stream>>>(W1, W1t, 768, 512);
  convert_wt<<<(512 * 512 + 255) / 256, 256, 0, stream>>>(W2, W2t, 512, 512);
  interp_gather<<<32768, 256, 0, stream>>>(x, idx3, w3, hcat);
  skip_copy<<<16384, 256, 0, stream>>>(x_skip, hcat);

  // GEMM1: [65536x768] x [768x512] -> h2 bf16 (ws)
  gemm_bias_relu<768, true><<<2048, 256, 0, stream>>>(hcat, W1t, b1, (void*)h2, 65536, 512);
  // GEMM2: [65536x512] x [512x512] -> d_out f32
  gemm_bias_relu<512, false><<<2048, 256, 0, stream>>>(h2, W2t, b2, d_out, 65536, 512);
}